// Round 3
// baseline (217.047 us; speedup 1.0000x reference)
//
#include <hip/hip_runtime.h>
#include <hip/hip_bf16.h>
#include <math.h>

// Problem constants
#define B_ 4
#define T_ 4096
#define C_ 1024
#define H_ 128
#define SCALE 0.08838834764831845f  // 1/sqrt(128)

typedef __attribute__((ext_vector_type(8))) short bf16x8;
typedef __attribute__((ext_vector_type(4))) float f32x4;

__device__ __forceinline__ unsigned short f2bf(float f) {
    union { float f; unsigned u; } x; x.f = f;
    unsigned r = x.u + 0x7FFF + ((x.u >> 16) & 1);
    return (unsigned short)(r >> 16);
}
__device__ __forceinline__ float bf2f(unsigned short u) {
    union { unsigned u; float f; } x; x.u = ((unsigned)u) << 16;
    return x.f;
}
__device__ __forceinline__ unsigned cvt_pk_bf16(float a, float b) {
    unsigned r;
    asm("v_cvt_pk_bf16_f32 %0, %1, %2" : "=v"(r) : "v"(a), "v"(b));
    return r;
}

// ---------------------------------------------------------------------------
// Kernel 1: W [C,H] fp32  ->  Wt [t][h][c] bf16  (transposed, cast)
// ---------------------------------------------------------------------------
__global__ __launch_bounds__(256) void wtrans_kernel(
        const float* __restrict__ Wk, const float* __restrict__ Wq,
        const float* __restrict__ Wv, unsigned short* __restrict__ Wt) {
    int tid = blockIdx.x * 256 + threadIdx.x;
    int t = tid >> 17;
    int r = tid & 131071;
    int c = r >> 7;
    int h = r & 127;
    const float* W = (t == 0) ? Wk : (t == 1) ? Wq : Wv;
    Wt[t * 131072 + h * 1024 + c] = f2bf(W[r]);
}

// ---------------------------------------------------------------------------
// Kernel 2: QKV projection GEMM.  M=16384, N=384, K=1024, bf16 MFMA.
// Wave owns 6 N-frags x 4 M-frags: 20 ds_read_b128 per 48 MFMA.
// ---------------------------------------------------------------------------
__global__ __launch_bounds__(256) void qkv_gemm(
        const float* __restrict__ x, const unsigned short* __restrict__ Wt,
        unsigned short* __restrict__ qkv) {
    __shared__ unsigned short As[64][72];
    __shared__ unsigned short Bs[384][72];

    const int m0 = blockIdx.x * 64;
    const int tid = threadIdx.x;
    const int lane = tid & 63;
    const int w = tid >> 6;
    const int fr = lane & 15;
    const int fq = lane >> 4;

    f32x4 acc[6][4];
#pragma unroll
    for (int i = 0; i < 6; i++)
#pragma unroll
        for (int rf = 0; rf < 4; rf++) acc[i][rf] = f32x4{0.f, 0.f, 0.f, 0.f};

    for (int k0 = 0; k0 < C_; k0 += 64) {
        __syncthreads();
        {
            int row = tid >> 2;
            int coff = (tid & 3) * 16;
            const float* src = x + (long)(m0 + row) * C_ + k0 + coff;
            unsigned short tmp[16];
#pragma unroll
            for (int i = 0; i < 4; i++) {
                float4 v = ((const float4*)src)[i];
                tmp[i*4+0] = f2bf(v.x); tmp[i*4+1] = f2bf(v.y);
                tmp[i*4+2] = f2bf(v.z); tmp[i*4+3] = f2bf(v.w);
            }
            uint4* dst = (uint4*)&As[row][coff];
            dst[0] = ((uint4*)tmp)[0];
            dst[1] = ((uint4*)tmp)[1];
        }
#pragma unroll
        for (int i = 0; i < 12; i++) {
            int idx = tid + i * 256;
            int row = idx >> 3;
            int coff = (idx & 7) * 8;
            *(uint4*)&Bs[row][coff] =
                *(const uint4*)(Wt + (long)row * 1024 + k0 + coff);
        }
        __syncthreads();

#pragma unroll
        for (int kk = 0; kk < 2; kk++) {
            bf16x8 a[4], bb[6];
#pragma unroll
            for (int rf = 0; rf < 4; rf++)
                a[rf] = *(const bf16x8*)&As[rf*16 + fr][kk*32 + fq*8];
#pragma unroll
            for (int i = 0; i < 6; i++)
                bb[i] = *(const bf16x8*)&Bs[(w*6 + i)*16 + fr][kk*32 + fq*8];
#pragma unroll
            for (int i = 0; i < 6; i++)
#pragma unroll
                for (int rf = 0; rf < 4; rf++)
                    acc[i][rf] = __builtin_amdgcn_mfma_f32_16x16x32_bf16(
                        a[rf], bb[i], acc[i][rf], 0, 0, 0);
        }
    }
#pragma unroll
    for (int i = 0; i < 6; i++) {
        int nf = w*6 + i;
        int t = nf >> 3;
        int col = (nf & 7) * 16 + fr;
#pragma unroll
        for (int rf = 0; rf < 4; rf++)
#pragma unroll
            for (int r = 0; r < 4; r++) {
                int row = m0 + rf*16 + fq*4 + r;
                qkv[(long)t * (16384L * 128) + (long)row * 128 + col] = f2bf(acc[i][rf][r]);
            }
    }
}

// ---------------------------------------------------------------------------
// Kernel 2b: V [B*T][128] -> vT [B][128][T]  (bf16 transpose via LDS)
// ---------------------------------------------------------------------------
__global__ __launch_bounds__(256) void vtrans_kernel(
        const unsigned short* __restrict__ v, unsigned short* __restrict__ vT) {
    __shared__ unsigned short tile[64][136];
    const int t0 = (blockIdx.x & 63) * 64;
    const int b = blockIdx.x >> 6;
    const int tid = threadIdx.x;
#pragma unroll
    for (int i = 0; i < 4; i++) {
        int idx = tid + i * 256;
        int tr = idx >> 4, coff = (idx & 15) * 8;
        *(uint4*)&tile[tr][coff] =
            *(const uint4*)(v + ((long)(b * T_ + t0 + tr)) * H_ + coff);
    }
    __syncthreads();
#pragma unroll
    for (int i = 0; i < 4; i++) {
        int idx = tid + i * 256;
        int h = idx >> 3, ts = (idx & 7) * 8;
        unsigned short tmp[8];
#pragma unroll
        for (int j = 0; j < 8; j++) tmp[j] = tile[ts + j][h];
        *(uint4*)(vT + ((long)(b * H_ + h)) * T_ + t0 + ts) = *(uint4*)tmp;
    }
}

// ---------------------------------------------------------------------------
// Kernel 3: causal flash attention, swapped-QK^T, in-register softmax.
// Grid 768: n -> b=(n&7)>>1 (XCD-batch affinity), idx2=(n>>3)*2+(n&1),
// j=idx2&63, part=idx2>>6 (KV split-3), qt=63-j (longest first).
// 4 waves x 16 q-rows. K double-buffered LDS (1 barrier/tile), V direct
// from vT (L2). P stays in registers via cvt_pk + shfl.
// ---------------------------------------------------------------------------
__global__ __launch_bounds__(256) void flash3_kernel(
        const unsigned short* __restrict__ qkv,
        const unsigned short* __restrict__ vT,
        unsigned short* __restrict__ po0, unsigned short* __restrict__ po1,
        unsigned short* __restrict__ po2,
        float* __restrict__ pm, float* __restrict__ pl) {
    __shared__ unsigned short k_lds[2][64][136];

    const int n = blockIdx.x;
    const int b = (n & 7) >> 1;
    const int idx2 = ((n >> 3) << 1) + (n & 1);   // 0..191
    const int j = idx2 & 63;
    const int part = idx2 >> 6;                   // 0..2
    const int qt = 63 - j;
    const int q0 = qt * 64;
    const int nt = qt + 1;
    const int t0 = (part * nt) / 3;
    const int t1 = ((part + 1) * nt) / 3;

    const int tid = threadIdx.x;
    const int w = tid >> 6;
    const int lane = tid & 63;
    const int fr = lane & 15;
    const int fq = lane >> 4;

    const unsigned short* kbase = qkv + (long)b * T_ * H_;
    const unsigned short* vbase = vT + (long)b * H_ * T_;

    // Q as B-operand frags: col = fr -> q-row q0+w*16+fr, k = ks*32+fq*8+j
    bf16x8 qf[4];
    {
        const unsigned short* qptr = qkv + 2097152 + ((long)b*T_ + q0 + w*16 + fr) * H_;
#pragma unroll
        for (int ks = 0; ks < 4; ks++)
            qf[ks] = *(const bf16x8*)(qptr + ks*32 + fq*8);
    }

    f32x4 acc[8];
#pragma unroll
    for (int i = 0; i < 8; i++) acc[i] = f32x4{0.f, 0.f, 0.f, 0.f};
    float m_r = -INFINITY, l_r = 0.f;
    const int qrow = q0 + w*16 + fr;

    uint4 g[4];
    int cur = 0;
    if (t0 < t1) {
        const int kv0 = t0 * 64;
#pragma unroll
        for (int i = 0; i < 4; i++) {
            int idx = tid + i * 256;
            int row = idx >> 4, coff = (idx & 15) * 8;
            g[i] = *(const uint4*)(kbase + (long)(kv0 + row) * H_ + coff);
        }
    }

    for (int t = t0; t < t1; ++t) {
        const int kv0 = t * 64;
        // write staged K tile to buf[cur] (compiler inserts vmcnt wait on g)
#pragma unroll
        for (int i = 0; i < 4; i++) {
            int idx = tid + i * 256;
            int row = idx >> 4, coff = (idx & 15) * 8;
            *(uint4*)&k_lds[cur][row][coff] = g[i];
        }
        // prefetch next K tile (latency hides under this tile's compute)
        if (t + 1 < t1) {
            const int kv0n = (t + 1) * 64;
#pragma unroll
            for (int i = 0; i < 4; i++) {
                int idx = tid + i * 256;
                int row = idx >> 4, coff = (idx & 15) * 8;
                g[i] = *(const uint4*)(kbase + (long)(kv0n + row) * H_ + coff);
            }
        }
        __syncthreads();

        // S^T = K Q^T : D col = q (fr), row = kv (fq*4+r within 16*sf)
        f32x4 s[4];
#pragma unroll
        for (int sf = 0; sf < 4; sf++) s[sf] = f32x4{0.f,0.f,0.f,0.f};
#pragma unroll
        for (int sf = 0; sf < 4; sf++)
#pragma unroll
            for (int ks = 0; ks < 4; ks++) {
                bf16x8 kf = *(const bf16x8*)&k_lds[cur][sf*16 + fr][ks*32 + fq*8];
                s[sf] = __builtin_amdgcn_mfma_f32_16x16x32_bf16(kf, qf[ks], s[sf], 0, 0, 0);
            }

        // scale + (diag-only) mask + in-lane row reduce
        float mx = -INFINITY;
        if (kv0 == q0) {
#pragma unroll
            for (int sf = 0; sf < 4; sf++)
#pragma unroll
                for (int r = 0; r < 4; r++) {
                    int kv = kv0 + sf*16 + fq*4 + r;
                    float sv = s[sf][r] * SCALE;
                    sv = (kv > qrow) ? -INFINITY : sv;
                    s[sf][r] = sv;
                    mx = fmaxf(mx, sv);
                }
        } else {
#pragma unroll
            for (int sf = 0; sf < 4; sf++)
#pragma unroll
                for (int r = 0; r < 4; r++) {
                    float sv = s[sf][r] * SCALE;
                    s[sf][r] = sv;
                    mx = fmaxf(mx, sv);
                }
        }
        mx = fmaxf(mx, __shfl_xor(mx, 16, 64));
        mx = fmaxf(mx, __shfl_xor(mx, 32, 64));

        float mn = fmaxf(m_r, mx);
        float alpha = __expf(m_r - mn);
        m_r = mn;
        float p[4][4];
        float sum = 0.f;
#pragma unroll
        for (int sf = 0; sf < 4; sf++)
#pragma unroll
            for (int r = 0; r < 4; r++) {
                float pv = __expf(s[sf][r] - mn);
                p[sf][r] = pv;
                sum += pv;
            }
        sum += __shfl_xor(sum, 16, 64);
        sum += __shfl_xor(sum, 32, 64);
        l_r = l_r * alpha + sum;
#pragma unroll
        for (int hf = 0; hf < 8; hf++)
#pragma unroll
            for (int r = 0; r < 4; r++) acc[hf][r] *= alpha;

        // pack P^T to bf16 pairs, shuffle into PV B-frags (kv-major)
        unsigned pw[8];
#pragma unroll
        for (int sf = 0; sf < 4; sf++) {
            pw[2*sf]   = cvt_pk_bf16(p[sf][0], p[sf][1]);
            pw[2*sf+1] = cvt_pk_bf16(p[sf][2], p[sf][3]);
        }
        unsigned pbu[2][4];
        pbu[0][0]=0;pbu[0][1]=0;pbu[0][2]=0;pbu[0][3]=0;
        pbu[1][0]=0;pbu[1][1]=0;pbu[1][2]=0;pbu[1][3]=0;
        const int L1 = fr + 16 * ((fq & 1) * 2);
        const int L2 = L1 + 16;
        const int sel = (fq >> 1) & 1;
#pragma unroll
        for (int sf = 0; sf < 4; sf++) {
            unsigned w0 = (unsigned)__shfl((int)pw[2*sf],   L1, 64);
            unsigned w1 = (unsigned)__shfl((int)pw[2*sf+1], L1, 64);
            unsigned w2 = (unsigned)__shfl((int)pw[2*sf],   L2, 64);
            unsigned w3 = (unsigned)__shfl((int)pw[2*sf+1], L2, 64);
            if ((sf & 1) == sel) {
                int k2 = sf >> 1;
                pbu[k2][0] = w0; pbu[k2][1] = w1; pbu[k2][2] = w2; pbu[k2][3] = w3;
            }
        }
        union { unsigned u[4]; bf16x8 v; } pb0c, pb1c;
#pragma unroll
        for (int i = 0; i < 4; i++) { pb0c.u[i] = pbu[0][i]; pb1c.u[i] = pbu[1][i]; }
        bf16x8 pb0 = pb0c.v, pb1 = pb1c.v;

        // O^T += V^T P^T : A = vT rows (h = hf*16+fr), direct from global/L2
#pragma unroll
        for (int hf = 0; hf < 8; hf++) {
            const unsigned short* vp = vbase + (long)(hf*16 + fr) * T_ + kv0 + fq*8;
            bf16x8 vf0 = *(const bf16x8*)(vp);
            bf16x8 vf1 = *(const bf16x8*)(vp + 32);
            acc[hf] = __builtin_amdgcn_mfma_f32_16x16x32_bf16(vf0, pb0, acc[hf], 0, 0, 0);
            acc[hf] = __builtin_amdgcn_mfma_f32_16x16x32_bf16(vf1, pb1, acc[hf], 0, 0, 0);
        }
        cur ^= 1;
    }

    // epilogue: O^T[h][q]: lane holds h = hf*16+fq*4+r (contiguous r), q = qrow
    unsigned short* po = (part == 0) ? po0 : (part == 1) ? po1 : po2;
    float linv = (l_r > 0.f) ? (1.0f / l_r) : 0.f;
    const long obase = ((long)b * T_ + qrow) * H_;
#pragma unroll
    for (int hf = 0; hf < 8; hf++) {
        unsigned u0 = cvt_pk_bf16(acc[hf][0] * linv, acc[hf][1] * linv);
        unsigned u1 = cvt_pk_bf16(acc[hf][2] * linv, acc[hf][3] * linv);
        uint2 uu; uu.x = u0; uu.y = u1;
        *(uint2*)(po + obase + hf*16 + fq*4) = uu;
    }
    if (fq == 0) {
        pm[part * 16384 + b * T_ + qrow] = m_r;
        pl[part * 16384 + b * T_ + qrow] = l_r;
    }
}

// ---------------------------------------------------------------------------
// Kernel 4: combine the three KV-parts
// ---------------------------------------------------------------------------
__global__ __launch_bounds__(256) void combine_kernel(
        const unsigned short* __restrict__ po0,
        const unsigned short* __restrict__ po1,
        const unsigned short* __restrict__ po2,
        const float* __restrict__ pm, const float* __restrict__ pl,
        float* __restrict__ out) {
    int idx = blockIdx.x * 256 + threadIdx.x;   // 0..262143
    int row = idx >> 4;                          // b*T + q
    int seg = idx & 15;
    float m0 = pm[row], m1 = pm[16384 + row], m2 = pm[32768 + row];
    float l0 = pl[row], l1 = pl[16384 + row], l2 = pl[32768 + row];
    float m = fmaxf(fmaxf(m0, m1), m2);
    float w0 = (l0 > 0.f) ? __expf(m0 - m) * l0 : 0.f;
    float w1 = (l1 > 0.f) ? __expf(m1 - m) * l1 : 0.f;
    float w2 = (l2 > 0.f) ? __expf(m2 - m) * l2 : 0.f;
    float inv = 1.0f / (w0 + w1 + w2);
    w0 *= inv; w1 *= inv; w2 *= inv;
    long off = (long)row * H_ + seg * 8;
    unsigned short ua[8], ub[8], uc[8];
    *(uint4*)ua = *(const uint4*)(po0 + off);
    *(uint4*)ub = *(const uint4*)(po1 + off);
    *(uint4*)uc = *(const uint4*)(po2 + off);
    float* o = out + off;
#pragma unroll
    for (int j2 = 0; j2 < 8; j2++)
        o[j2] = w0 * bf2f(ua[j2]) + w1 * bf2f(ub[j2]) + w2 * bf2f(uc[j2]);
}

// ---------------------------------------------------------------------------
extern "C" void kernel_launch(void* const* d_in, const int* in_sizes, int n_in,
                              void* d_out, int out_size, void* d_ws, size_t ws_size,
                              hipStream_t stream) {
    (void)in_sizes; (void)n_in; (void)out_size; (void)ws_size;
    const float* x  = (const float*)d_in[0];
    const float* Wk = (const float*)d_in[1];
    const float* Wq = (const float*)d_in[2];
    const float* Wv = (const float*)d_in[3];
    float* out = (float*)d_out;

    // ws layout (shorts). pm/pl alias Wt (dead by flash time); po2 aliases
    // the qkv v-region (dead after vtrans). Total ~25.9 MB.
    unsigned short* Wt  = (unsigned short*)d_ws;       // 393216 shorts
    unsigned short* qkv = Wt + 393216;                 // 3 x 2097152 (k,q,v)
    unsigned short* vT  = qkv + 6291456;               // 2097152
    unsigned short* po0 = vT + 2097152;                // 2097152
    unsigned short* po1 = po0 + 2097152;               // 2097152
    unsigned short* po2 = qkv + 4194304;               // aliases v region
    float* pm = (float*)d_ws;                          // 49152 floats (alias Wt)
    float* pl = pm + 49152;                            // 49152 floats (alias Wt)

    wtrans_kernel<<<1536, 256, 0, stream>>>(Wk, Wq, Wv, Wt);
    qkv_gemm<<<256, 256, 0, stream>>>(x, Wt, qkv);
    vtrans_kernel<<<256, 256, 0, stream>>>(qkv + 4194304, vT);
    flash3_kernel<<<768, 256, 0, stream>>>(qkv, vT, po0, po1, po2, pm, pl);
    combine_kernel<<<1024, 256, 0, stream>>>(po0, po1, po2, pm, pl, out);
}

// Round 4
// 210.180 us; speedup vs baseline: 1.0327x; 1.0327x over previous
//
#include <hip/hip_runtime.h>
#include <hip/hip_bf16.h>
#include <math.h>

// Problem constants
#define B_ 4
#define T_ 4096
#define C_ 1024
#define H_ 128
#define SCALE 0.08838834764831845f  // 1/sqrt(128)

typedef __attribute__((ext_vector_type(8))) short bf16x8;
typedef __attribute__((ext_vector_type(4))) float f32x4;

__device__ __forceinline__ unsigned short f2bf(float f) {
    union { float f; unsigned u; } x; x.f = f;
    unsigned r = x.u + 0x7FFF + ((x.u >> 16) & 1);
    return (unsigned short)(r >> 16);
}
__device__ __forceinline__ float bf2f(unsigned short u) {
    union { unsigned u; float f; } x; x.u = ((unsigned)u) << 16;
    return x.f;
}
__device__ __forceinline__ unsigned cvt_pk_bf16(float a, float b) {
    unsigned r;
    asm("v_cvt_pk_bf16_f32 %0, %1, %2" : "=v"(r) : "v"(a), "v"(b));
    return r;
}

// ---------------------------------------------------------------------------
// Kernel 1: W [C,H] fp32  ->  Wt [t][h][c] bf16  (transposed, cast)
// ---------------------------------------------------------------------------
__global__ __launch_bounds__(256) void wtrans_kernel(
        const float* __restrict__ Wk, const float* __restrict__ Wq,
        const float* __restrict__ Wv, unsigned short* __restrict__ Wt) {
    int tid = blockIdx.x * 256 + threadIdx.x;
    int t = tid >> 17;
    int r = tid & 131071;
    int c = r >> 7;
    int h = r & 127;
    const float* W = (t == 0) ? Wk : (t == 1) ? Wq : Wv;
    Wt[t * 131072 + h * 1024 + c] = f2bf(W[r]);
}

// ---------------------------------------------------------------------------
// Kernel 2: QKV projection GEMM.  M=16384, N=384, K=1024, bf16 MFMA.
// ---------------------------------------------------------------------------
__global__ __launch_bounds__(256) void qkv_gemm(
        const float* __restrict__ x, const unsigned short* __restrict__ Wt,
        unsigned short* __restrict__ qkv) {
    __shared__ unsigned short As[64][72];
    __shared__ unsigned short Bs[384][72];

    const int m0 = blockIdx.x * 64;
    const int tid = threadIdx.x;
    const int lane = tid & 63;
    const int w = tid >> 6;
    const int fr = lane & 15;
    const int fq = lane >> 4;

    f32x4 acc[6][4];
#pragma unroll
    for (int i = 0; i < 6; i++)
#pragma unroll
        for (int rf = 0; rf < 4; rf++) acc[i][rf] = f32x4{0.f, 0.f, 0.f, 0.f};

    for (int k0 = 0; k0 < C_; k0 += 64) {
        __syncthreads();
        {
            int row = tid >> 2;
            int coff = (tid & 3) * 16;
            const float* src = x + (long)(m0 + row) * C_ + k0 + coff;
            unsigned short tmp[16];
#pragma unroll
            for (int i = 0; i < 4; i++) {
                float4 v = ((const float4*)src)[i];
                tmp[i*4+0] = f2bf(v.x); tmp[i*4+1] = f2bf(v.y);
                tmp[i*4+2] = f2bf(v.z); tmp[i*4+3] = f2bf(v.w);
            }
            uint4* dst = (uint4*)&As[row][coff];
            dst[0] = ((uint4*)tmp)[0];
            dst[1] = ((uint4*)tmp)[1];
        }
#pragma unroll
        for (int i = 0; i < 12; i++) {
            int idx = tid + i * 256;
            int row = idx >> 3;
            int coff = (idx & 7) * 8;
            *(uint4*)&Bs[row][coff] =
                *(const uint4*)(Wt + (long)row * 1024 + k0 + coff);
        }
        __syncthreads();

#pragma unroll
        for (int kk = 0; kk < 2; kk++) {
            bf16x8 a[4], bb[6];
#pragma unroll
            for (int rf = 0; rf < 4; rf++)
                a[rf] = *(const bf16x8*)&As[rf*16 + fr][kk*32 + fq*8];
#pragma unroll
            for (int i = 0; i < 6; i++)
                bb[i] = *(const bf16x8*)&Bs[(w*6 + i)*16 + fr][kk*32 + fq*8];
#pragma unroll
            for (int i = 0; i < 6; i++)
#pragma unroll
                for (int rf = 0; rf < 4; rf++)
                    acc[i][rf] = __builtin_amdgcn_mfma_f32_16x16x32_bf16(
                        a[rf], bb[i], acc[i][rf], 0, 0, 0);
        }
    }
#pragma unroll
    for (int i = 0; i < 6; i++) {
        int nf = w*6 + i;
        int t = nf >> 3;
        int col = (nf & 7) * 16 + fr;
#pragma unroll
        for (int rf = 0; rf < 4; rf++)
#pragma unroll
            for (int r = 0; r < 4; r++) {
                int row = m0 + rf*16 + fq*4 + r;
                qkv[(long)t * (16384L * 128) + (long)row * 128 + col] = f2bf(acc[i][rf][r]);
            }
    }
}

// ---------------------------------------------------------------------------
// Kernel 2b: V [B*T][128] -> vT [B][128][T]  (bf16 transpose via LDS)
// ---------------------------------------------------------------------------
__global__ __launch_bounds__(256) void vtrans_kernel(
        const unsigned short* __restrict__ v, unsigned short* __restrict__ vT) {
    __shared__ unsigned short tile[64][136];
    const int t0 = (blockIdx.x & 63) * 64;
    const int b = blockIdx.x >> 6;
    const int tid = threadIdx.x;
#pragma unroll
    for (int i = 0; i < 4; i++) {
        int idx = tid + i * 256;
        int tr = idx >> 4, coff = (idx & 15) * 8;
        *(uint4*)&tile[tr][coff] =
            *(const uint4*)(v + ((long)(b * T_ + t0 + tr)) * H_ + coff);
    }
    __syncthreads();
#pragma unroll
    for (int i = 0; i < 4; i++) {
        int idx = tid + i * 256;
        int h = idx >> 3, ts = (idx & 7) * 8;
        unsigned short tmp[8];
#pragma unroll
        for (int j = 0; j < 8; j++) tmp[j] = tile[ts + j][h];
        *(uint4*)(vT + ((long)(b * H_ + h)) * T_ + t0 + ts) = *(uint4*)tmp;
    }
}

// ---------------------------------------------------------------------------
// Kernel 3: causal flash attention, swapped-QK^T, in-register softmax,
// K AND V staged in LDS (single-buffered) with register prefetch of both.
// Grid 768: n -> b=(n&7)>>1, idx2=(n>>3)*2+(n&1), j=idx2&63, part=idx2>>6,
// qt=63-j (longest first), KV split-3.
// ---------------------------------------------------------------------------
__global__ __launch_bounds__(256, 3) void flash4_kernel(
        const unsigned short* __restrict__ qkv,
        const unsigned short* __restrict__ vT,
        unsigned short* __restrict__ po0, unsigned short* __restrict__ po1,
        unsigned short* __restrict__ po2,
        float* __restrict__ pm, float* __restrict__ pl) {
    __shared__ unsigned short k_lds[64][136];   // 17.4 KB
    __shared__ unsigned short v_lds[128][72];   // 18.4 KB  (v_lds[h][kv])

    const int n = blockIdx.x;
    const int b = (n & 7) >> 1;
    const int idx2 = ((n >> 3) << 1) + (n & 1);   // 0..191
    const int j = idx2 & 63;
    const int part = idx2 >> 6;                   // 0..2
    const int qt = 63 - j;
    const int q0 = qt * 64;
    const int nt = qt + 1;
    const int t0 = (part * nt) / 3;
    const int t1 = ((part + 1) * nt) / 3;

    const int tid = threadIdx.x;
    const int w = tid >> 6;
    const int lane = tid & 63;
    const int fr = lane & 15;
    const int fq = lane >> 4;

    const unsigned short* kbase = qkv + (long)b * T_ * H_;
    const unsigned short* vbase = vT + (long)b * H_ * T_;

    // Q as B-operand frags: col = fr -> q-row q0+w*16+fr, k = ks*32+fq*8+j
    bf16x8 qf[4];
    {
        const unsigned short* qptr = qkv + 2097152 + ((long)b*T_ + q0 + w*16 + fr) * H_;
#pragma unroll
        for (int ks = 0; ks < 4; ks++)
            qf[ks] = *(const bf16x8*)(qptr + ks*32 + fq*8);
    }

    f32x4 acc[8];
#pragma unroll
    for (int i = 0; i < 8; i++) acc[i] = f32x4{0.f, 0.f, 0.f, 0.f};
    float m_r = -INFINITY, l_r = 0.f;
    const int qrow = q0 + w*16 + fr;

    // staging registers for K (g) and V (gv)
    uint4 g[4], gv[4];
    const int krow = tid >> 2;                  // K: thread covers rows tid>>2? no:
    // K indices: idx = tid + i*256 -> row=idx>>4, coff=(idx&15)*8
    // V indices: idx = tid + i*256 -> h=idx>>3,  coff=(idx&7)*8
    if (t0 < t1) {
        const int kv0 = t0 * 64;
#pragma unroll
        for (int i = 0; i < 4; i++) {
            int idx = tid + i * 256;
            g[i]  = *(const uint4*)(kbase + (long)(kv0 + (idx >> 4)) * H_ + (idx & 15) * 8);
            gv[i] = *(const uint4*)(vbase + (long)(idx >> 3) * T_ + kv0 + (idx & 7) * 8);
        }
    }
    (void)krow;

    for (int t = t0; t < t1; ++t) {
        const int kv0 = t * 64;
        __syncthreads();   // previous tile's LDS reads complete
#pragma unroll
        for (int i = 0; i < 4; i++) {
            int idx = tid + i * 256;
            *(uint4*)&k_lds[idx >> 4][(idx & 15) * 8] = g[i];
            *(uint4*)&v_lds[idx >> 3][(idx & 7) * 8] = gv[i];
        }
        // prefetch next tile into regs; latency hides under this tile's compute
        if (t + 1 < t1) {
            const int kv0n = kv0 + 64;
#pragma unroll
            for (int i = 0; i < 4; i++) {
                int idx = tid + i * 256;
                g[i]  = *(const uint4*)(kbase + (long)(kv0n + (idx >> 4)) * H_ + (idx & 15) * 8);
                gv[i] = *(const uint4*)(vbase + (long)(idx >> 3) * T_ + kv0n + (idx & 7) * 8);
            }
        }
        __syncthreads();   // LDS tile ready

        // S^T = K Q^T : D col = q (fr), row = kv (16*sf + fq*4 + r)
        f32x4 s[4];
#pragma unroll
        for (int sf = 0; sf < 4; sf++) s[sf] = f32x4{0.f,0.f,0.f,0.f};
        __builtin_amdgcn_s_setprio(1);
#pragma unroll
        for (int sf = 0; sf < 4; sf++)
#pragma unroll
            for (int ks = 0; ks < 4; ks++) {
                bf16x8 kf = *(const bf16x8*)&k_lds[sf*16 + fr][ks*32 + fq*8];
                s[sf] = __builtin_amdgcn_mfma_f32_16x16x32_bf16(kf, qf[ks], s[sf], 0, 0, 0);
            }
        __builtin_amdgcn_s_setprio(0);

        // scale + (diag-only) mask + in-lane row reduce
        float mx = -INFINITY;
        if (kv0 == q0) {
#pragma unroll
            for (int sf = 0; sf < 4; sf++)
#pragma unroll
                for (int r = 0; r < 4; r++) {
                    int kv = kv0 + sf*16 + fq*4 + r;
                    float sv = s[sf][r] * SCALE;
                    sv = (kv > qrow) ? -INFINITY : sv;
                    s[sf][r] = sv;
                    mx = fmaxf(mx, sv);
                }
        } else {
#pragma unroll
            for (int sf = 0; sf < 4; sf++)
#pragma unroll
                for (int r = 0; r < 4; r++) {
                    float sv = s[sf][r] * SCALE;
                    s[sf][r] = sv;
                    mx = fmaxf(mx, sv);
                }
        }
        mx = fmaxf(mx, __shfl_xor(mx, 16, 64));
        mx = fmaxf(mx, __shfl_xor(mx, 32, 64));

        float mn = fmaxf(m_r, mx);
        float alpha = __expf(m_r - mn);
        m_r = mn;
        float p[4][4];
        float sum = 0.f;
#pragma unroll
        for (int sf = 0; sf < 4; sf++)
#pragma unroll
            for (int r = 0; r < 4; r++) {
                float pv = __expf(s[sf][r] - mn);
                p[sf][r] = pv;
                sum += pv;
            }
        sum += __shfl_xor(sum, 16, 64);
        sum += __shfl_xor(sum, 32, 64);
        l_r = l_r * alpha + sum;
#pragma unroll
        for (int hf = 0; hf < 8; hf++)
#pragma unroll
            for (int r = 0; r < 4; r++) acc[hf][r] *= alpha;

        // pack P^T to bf16 pairs, shuffle into PV B-frags (kv-major)
        unsigned pw[8];
#pragma unroll
        for (int sf = 0; sf < 4; sf++) {
            pw[2*sf]   = cvt_pk_bf16(p[sf][0], p[sf][1]);
            pw[2*sf+1] = cvt_pk_bf16(p[sf][2], p[sf][3]);
        }
        unsigned pbu[2][4];
        pbu[0][0]=0;pbu[0][1]=0;pbu[0][2]=0;pbu[0][3]=0;
        pbu[1][0]=0;pbu[1][1]=0;pbu[1][2]=0;pbu[1][3]=0;
        const int L1 = fr + 16 * ((fq & 1) * 2);
        const int L2 = L1 + 16;
        const int sel = (fq >> 1) & 1;
#pragma unroll
        for (int sf = 0; sf < 4; sf++) {
            unsigned w0 = (unsigned)__shfl((int)pw[2*sf],   L1, 64);
            unsigned w1 = (unsigned)__shfl((int)pw[2*sf+1], L1, 64);
            unsigned w2 = (unsigned)__shfl((int)pw[2*sf],   L2, 64);
            unsigned w3 = (unsigned)__shfl((int)pw[2*sf+1], L2, 64);
            if ((sf & 1) == sel) {
                int k2 = sf >> 1;
                pbu[k2][0] = w0; pbu[k2][1] = w1; pbu[k2][2] = w2; pbu[k2][3] = w3;
            }
        }
        union { unsigned u[4]; bf16x8 v; } pb0c, pb1c;
#pragma unroll
        for (int i = 0; i < 4; i++) { pb0c.u[i] = pbu[0][i]; pb1c.u[i] = pbu[1][i]; }
        bf16x8 pb0 = pb0c.v, pb1 = pb1c.v;

        // O^T += V^T P^T : A-frag rows h = hf*16+fr from v_lds
        __builtin_amdgcn_s_setprio(1);
#pragma unroll
        for (int hf = 0; hf < 8; hf++) {
            bf16x8 vf0 = *(const bf16x8*)&v_lds[hf*16 + fr][fq*8];
            bf16x8 vf1 = *(const bf16x8*)&v_lds[hf*16 + fr][32 + fq*8];
            acc[hf] = __builtin_amdgcn_mfma_f32_16x16x32_bf16(vf0, pb0, acc[hf], 0, 0, 0);
            acc[hf] = __builtin_amdgcn_mfma_f32_16x16x32_bf16(vf1, pb1, acc[hf], 0, 0, 0);
        }
        __builtin_amdgcn_s_setprio(0);
    }

    // epilogue: O^T[h][q]: lane holds h = hf*16+fq*4+r, q = qrow
    unsigned short* po = (part == 0) ? po0 : (part == 1) ? po1 : po2;
    float linv = (l_r > 0.f) ? (1.0f / l_r) : 0.f;
    const long obase = ((long)b * T_ + qrow) * H_;
#pragma unroll
    for (int hf = 0; hf < 8; hf++) {
        unsigned u0 = cvt_pk_bf16(acc[hf][0] * linv, acc[hf][1] * linv);
        unsigned u1 = cvt_pk_bf16(acc[hf][2] * linv, acc[hf][3] * linv);
        uint2 uu; uu.x = u0; uu.y = u1;
        *(uint2*)(po + obase + hf*16 + fq*4) = uu;
    }
    if (fq == 0) {
        pm[part * 16384 + b * T_ + qrow] = m_r;
        pl[part * 16384 + b * T_ + qrow] = l_r;
    }
}

// ---------------------------------------------------------------------------
// Kernel 4: combine the three KV-parts
// ---------------------------------------------------------------------------
__global__ __launch_bounds__(256) void combine_kernel(
        const unsigned short* __restrict__ po0,
        const unsigned short* __restrict__ po1,
        const unsigned short* __restrict__ po2,
        const float* __restrict__ pm, const float* __restrict__ pl,
        float* __restrict__ out) {
    int idx = blockIdx.x * 256 + threadIdx.x;   // 0..262143
    int row = idx >> 4;                          // b*T + q
    int seg = idx & 15;
    float m0 = pm[row], m1 = pm[16384 + row], m2 = pm[32768 + row];
    float l0 = pl[row], l1 = pl[16384 + row], l2 = pl[32768 + row];
    float m = fmaxf(fmaxf(m0, m1), m2);
    float w0 = (l0 > 0.f) ? __expf(m0 - m) * l0 : 0.f;
    float w1 = (l1 > 0.f) ? __expf(m1 - m) * l1 : 0.f;
    float w2 = (l2 > 0.f) ? __expf(m2 - m) * l2 : 0.f;
    float inv = 1.0f / (w0 + w1 + w2);
    w0 *= inv; w1 *= inv; w2 *= inv;
    long off = (long)row * H_ + seg * 8;
    unsigned short ua[8], ub[8], uc[8];
    *(uint4*)ua = *(const uint4*)(po0 + off);
    *(uint4*)ub = *(const uint4*)(po1 + off);
    *(uint4*)uc = *(const uint4*)(po2 + off);
    float* o = out + off;
#pragma unroll
    for (int j2 = 0; j2 < 8; j2++)
        o[j2] = w0 * bf2f(ua[j2]) + w1 * bf2f(ub[j2]) + w2 * bf2f(uc[j2]);
}

// ---------------------------------------------------------------------------
extern "C" void kernel_launch(void* const* d_in, const int* in_sizes, int n_in,
                              void* d_out, int out_size, void* d_ws, size_t ws_size,
                              hipStream_t stream) {
    (void)in_sizes; (void)n_in; (void)out_size; (void)ws_size;
    const float* x  = (const float*)d_in[0];
    const float* Wk = (const float*)d_in[1];
    const float* Wq = (const float*)d_in[2];
    const float* Wv = (const float*)d_in[3];
    float* out = (float*)d_out;

    // ws layout (shorts). pm/pl alias Wt (dead by flash time); po2 aliases
    // the qkv v-region (dead after vtrans). Total ~25.9 MB.
    unsigned short* Wt  = (unsigned short*)d_ws;       // 393216 shorts
    unsigned short* qkv = Wt + 393216;                 // 3 x 2097152 (k,q,v)
    unsigned short* vT  = qkv + 6291456;               // 2097152
    unsigned short* po0 = vT + 2097152;                // 2097152
    unsigned short* po1 = po0 + 2097152;               // 2097152
    unsigned short* po2 = qkv + 4194304;               // aliases v region
    float* pm = (float*)d_ws;                          // 49152 floats (alias Wt)
    float* pl = pm + 49152;                            // 49152 floats (alias Wt)

    wtrans_kernel<<<1536, 256, 0, stream>>>(Wk, Wq, Wv, Wt);
    qkv_gemm<<<256, 256, 0, stream>>>(x, Wt, qkv);
    vtrans_kernel<<<256, 256, 0, stream>>>(qkv + 4194304, vT);
    flash4_kernel<<<768, 256, 0, stream>>>(qkv, vT, po0, po1, po2, pm, pl);
    combine_kernel<<<1024, 256, 0, stream>>>(po0, po1, po2, pm, pl, out);
}

// Round 5
// 108.726 us; speedup vs baseline: 1.9963x; 1.9331x over previous
//
#include <hip/hip_runtime.h>
#include <hip/hip_bf16.h>
#include <math.h>

// Problem constants
#define B_ 4
#define T_ 4096
#define C_ 1024
#define H_ 128
#define SCALE 0.08838834764831845f  // 1/sqrt(128)

typedef __attribute__((ext_vector_type(8))) short bf16x8;
typedef __attribute__((ext_vector_type(4))) float f32x4;

__device__ __forceinline__ unsigned short f2bf(float f) {
    union { float f; unsigned u; } x; x.f = f;
    unsigned r = x.u + 0x7FFF + ((x.u >> 16) & 1);
    return (unsigned short)(r >> 16);
}
__device__ __forceinline__ float bf2f(unsigned short u) {
    union { unsigned u; float f; } x; x.u = ((unsigned)u) << 16;
    return x.f;
}
__device__ __forceinline__ unsigned cvt_pk_bf16(float a, float b) {
    unsigned r;
    asm("v_cvt_pk_bf16_f32 %0, %1, %2" : "=v"(r) : "v"(a), "v"(b));
    return r;
}

// async global->LDS, 16B per lane. gsrc: per-lane global addr; ldst: wave-uniform base.
#define GLOAD16(gsrc, ldst)                                                        \
    __builtin_amdgcn_global_load_lds(                                              \
        (const __attribute__((address_space(1))) unsigned int*)(gsrc),             \
        (__attribute__((address_space(3))) unsigned int*)(ldst), 16, 0, 0)

// ---------------------------------------------------------------------------
// Kernel 1: W [C,H] fp32  ->  Wt [t][h][c] bf16  (transposed, cast)
// ---------------------------------------------------------------------------
__global__ __launch_bounds__(256) void wtrans_kernel(
        const float* __restrict__ Wk, const float* __restrict__ Wq,
        const float* __restrict__ Wv, unsigned short* __restrict__ Wt) {
    int tid = blockIdx.x * 256 + threadIdx.x;
    int t = tid >> 17;
    int r = tid & 131071;
    int c = r >> 7;
    int h = r & 127;
    const float* W = (t == 0) ? Wk : (t == 1) ? Wq : Wv;
    Wt[t * 131072 + h * 1024 + c] = f2bf(W[r]);
}

// ---------------------------------------------------------------------------
// Kernel 2: QKV projection GEMM.  M=16384, N=384, K=1024, bf16 MFMA.
// ---------------------------------------------------------------------------
__global__ __launch_bounds__(256) void qkv_gemm(
        const float* __restrict__ x, const unsigned short* __restrict__ Wt,
        unsigned short* __restrict__ qkv) {
    __shared__ unsigned short As[64][72];
    __shared__ unsigned short Bs[384][72];

    const int m0 = blockIdx.x * 64;
    const int tid = threadIdx.x;
    const int lane = tid & 63;
    const int w = tid >> 6;
    const int fr = lane & 15;
    const int fq = lane >> 4;

    f32x4 acc[6][4];
#pragma unroll
    for (int i = 0; i < 6; i++)
#pragma unroll
        for (int rf = 0; rf < 4; rf++) acc[i][rf] = f32x4{0.f, 0.f, 0.f, 0.f};

    for (int k0 = 0; k0 < C_; k0 += 64) {
        __syncthreads();
        {
            int row = tid >> 2;
            int coff = (tid & 3) * 16;
            const float* src = x + (long)(m0 + row) * C_ + k0 + coff;
            unsigned short tmp[16];
#pragma unroll
            for (int i = 0; i < 4; i++) {
                float4 v = ((const float4*)src)[i];
                tmp[i*4+0] = f2bf(v.x); tmp[i*4+1] = f2bf(v.y);
                tmp[i*4+2] = f2bf(v.z); tmp[i*4+3] = f2bf(v.w);
            }
            uint4* dst = (uint4*)&As[row][coff];
            dst[0] = ((uint4*)tmp)[0];
            dst[1] = ((uint4*)tmp)[1];
        }
#pragma unroll
        for (int i = 0; i < 12; i++) {
            int idx = tid + i * 256;
            int row = idx >> 3;
            int coff = (idx & 7) * 8;
            *(uint4*)&Bs[row][coff] =
                *(const uint4*)(Wt + (long)row * 1024 + k0 + coff);
        }
        __syncthreads();

#pragma unroll
        for (int kk = 0; kk < 2; kk++) {
            bf16x8 a[4], bb[6];
#pragma unroll
            for (int rf = 0; rf < 4; rf++)
                a[rf] = *(const bf16x8*)&As[rf*16 + fr][kk*32 + fq*8];
#pragma unroll
            for (int i = 0; i < 6; i++)
                bb[i] = *(const bf16x8*)&Bs[(w*6 + i)*16 + fr][kk*32 + fq*8];
#pragma unroll
            for (int i = 0; i < 6; i++)
#pragma unroll
                for (int rf = 0; rf < 4; rf++)
                    acc[i][rf] = __builtin_amdgcn_mfma_f32_16x16x32_bf16(
                        a[rf], bb[i], acc[i][rf], 0, 0, 0);
        }
    }
#pragma unroll
    for (int i = 0; i < 6; i++) {
        int nf = w*6 + i;
        int t = nf >> 3;
        int col = (nf & 7) * 16 + fr;
#pragma unroll
        for (int rf = 0; rf < 4; rf++)
#pragma unroll
            for (int r = 0; r < 4; r++) {
                int row = m0 + rf*16 + fq*4 + r;
                qkv[(long)t * (16384L * 128) + (long)row * 128 + col] = f2bf(acc[i][rf][r]);
            }
    }
}

// ---------------------------------------------------------------------------
// Kernel 2b: V [B*T][128] -> vT [B][128][T]  (bf16 transpose via LDS)
// ---------------------------------------------------------------------------
__global__ __launch_bounds__(256) void vtrans_kernel(
        const unsigned short* __restrict__ v, unsigned short* __restrict__ vT) {
    __shared__ unsigned short tile[64][136];
    const int t0 = (blockIdx.x & 63) * 64;
    const int b = blockIdx.x >> 6;
    const int tid = threadIdx.x;
#pragma unroll
    for (int i = 0; i < 4; i++) {
        int idx = tid + i * 256;
        int tr = idx >> 4, coff = (idx & 15) * 8;
        *(uint4*)&tile[tr][coff] =
            *(const uint4*)(v + ((long)(b * T_ + t0 + tr)) * H_ + coff);
    }
    __syncthreads();
#pragma unroll
    for (int i = 0; i < 4; i++) {
        int idx = tid + i * 256;
        int h = idx >> 3, ts = (idx & 7) * 8;
        unsigned short tmp[8];
#pragma unroll
        for (int j = 0; j < 8; j++) tmp[j] = tile[ts + j][h];
        *(uint4*)(vT + ((long)(b * H_ + h)) * T_ + t0 + ts) = *(uint4*)tmp;
    }
}

// ---------------------------------------------------------------------------
// Kernel 3: causal flash attention. Swapped-QK^T in-register softmax.
// K and V staged via global_load_lds (async, zero staging VGPRs) into
// double-buffered UNPADDED LDS with XOR swizzle (colbyte ^= (row&7)<<4):
// linear LDS dest + inverse-swizzled per-lane global src + swizzled ds_read.
// Pipeline per tile: barrier / issue t+1 (8 ops) / vmcnt(8) / barrier / compute.
// Grid 768: b=(n&7)>>1, idx2=(n>>3)*2+(n&1), j=idx2&63, part=idx2>>6, qt=63-j.
// ---------------------------------------------------------------------------
__global__ __launch_bounds__(256, 2) void flash5_kernel(
        const unsigned short* __restrict__ qkv,
        const unsigned short* __restrict__ vT,
        unsigned short* __restrict__ po0, unsigned short* __restrict__ po1,
        unsigned short* __restrict__ po2,
        float* __restrict__ pm, float* __restrict__ pl) {
    __shared__ unsigned short k_lds[2][64][128];   // 32 KB, swizzled
    __shared__ unsigned short v_lds[2][128][64];   // 32 KB, swizzled (v_lds[h][kv])

    const int n = blockIdx.x;
    const int b = (n & 7) >> 1;
    const int idx2 = ((n >> 3) << 1) + (n & 1);   // 0..191
    const int j = idx2 & 63;
    const int part = idx2 >> 6;                   // 0..2
    const int qt = 63 - j;
    const int q0 = qt * 64;
    const int nt = qt + 1;
    const int t0 = (part * nt) / 3;
    const int t1 = ((part + 1) * nt) / 3;

    const int tid = threadIdx.x;
    const int w = tid >> 6;
    const int lane = tid & 63;
    const int fr = lane & 15;
    const int fq = lane >> 4;

    const unsigned short* kbase = qkv + (long)b * T_ * H_;
    const unsigned short* vbase = vT + (long)b * H_ * T_;

    // ---- staging address constants (per lane) ----
    // K: chunk c = w + 4i covers rows 4c..4c+3; lane covers (row, 16B col chunk)
    const int krow = 4 * w + (lane >> 4);                    // +16*i per chunk
    const int kcolb = ((lane & 15) << 4) ^ ((krow & 7) << 4);  // inverse-swizzled col (bytes)
    // V: chunk c = w + 4i covers rows 8c..8c+7 of vT (h-major)
    const int vrow = lane >> 3;                               // 0..7 (h&7)
    const int vcolb = ((lane & 7) << 4) ^ (vrow << 4);
    // wave-uniform LDS chunk base (shorts): w*512 + i*2048 within each buffer
    unsigned short* const klds_flat = &k_lds[0][0][0];
    unsigned short* const vlds_flat = &v_lds[0][0][0];

    // ---- MFMA read constants ----
    const int scol = ((fq ^ (fr & 7)) << 4);   // swizzled col base (bytes)

    // Q as B-operand frags: col = fr -> q-row q0+w*16+fr, k = ks*32+fq*8+j
    bf16x8 qf[4];
    {
        const unsigned short* qptr = qkv + 2097152 + ((long)b*T_ + q0 + w*16 + fr) * H_;
#pragma unroll
        for (int ks = 0; ks < 4; ks++)
            qf[ks] = *(const bf16x8*)(qptr + ks*32 + fq*8);
    }

    f32x4 acc[8];
#pragma unroll
    for (int i = 0; i < 8; i++) acc[i] = f32x4{0.f, 0.f, 0.f, 0.f};
    float m_r = -INFINITY, l_r = 0.f;
    const int qrow = q0 + w*16 + fr;

    int cur = 0;
    // prologue: issue tile t0 into buffer 0
    if (t0 < t1) {
        const int kv0 = t0 * 64;
#pragma unroll
        for (int i = 0; i < 4; i++) {
            GLOAD16(kbase + (long)(kv0 + krow + 16*i) * 128 + (kcolb >> 1),
                    klds_flat + w*512 + i*2048);
            GLOAD16(vbase + (long)(8*w + 32*i + vrow) * 4096 + kv0 + (vcolb >> 1),
                    vlds_flat + w*512 + i*2048);
        }
    }

    for (int t = t0; t < t1; ++t) {
        const int kv0 = t * 64;
        __syncthreads();   // all waves done reading buf[cur^1] (tile t-1)
        if (t + 1 < t1) {
            const int kv0n = kv0 + 64;
            const int boff = (cur ^ 1) * 8192;
#pragma unroll
            for (int i = 0; i < 4; i++) {
                GLOAD16(kbase + (long)(kv0n + krow + 16*i) * 128 + (kcolb >> 1),
                        klds_flat + boff + w*512 + i*2048);
                GLOAD16(vbase + (long)(8*w + 32*i + vrow) * 4096 + kv0n + (vcolb >> 1),
                        vlds_flat + boff + w*512 + i*2048);
            }
            asm volatile("s_waitcnt vmcnt(8)" ::: "memory");  // own tile-t loads done
        } else {
            asm volatile("s_waitcnt vmcnt(0)" ::: "memory");
        }
        __syncthreads();   // all waves' tile-t chunks visible in LDS

        const char* kl = (const char*)k_lds + cur*16384 + fr*256;
        const char* vl = (const char*)v_lds + cur*16384 + fr*128;

        // S^T = K Q^T : D col = q (fr), row = kv (16*sf + fq*4 + r)
        f32x4 s[4];
#pragma unroll
        for (int sf = 0; sf < 4; sf++) s[sf] = f32x4{0.f,0.f,0.f,0.f};
        __builtin_amdgcn_s_setprio(1);
#pragma unroll
        for (int sf = 0; sf < 4; sf++)
#pragma unroll
            for (int ks = 0; ks < 4; ks++) {
                bf16x8 kf = *(const bf16x8*)(kl + sf*4096 + (scol ^ (ks << 6)));
                s[sf] = __builtin_amdgcn_mfma_f32_16x16x32_bf16(kf, qf[ks], s[sf], 0, 0, 0);
            }
        __builtin_amdgcn_s_setprio(0);

        // scale + (diag-only) mask + in-lane row reduce
        float mx = -INFINITY;
        if (kv0 == q0) {
#pragma unroll
            for (int sf = 0; sf < 4; sf++)
#pragma unroll
                for (int r = 0; r < 4; r++) {
                    int kv = kv0 + sf*16 + fq*4 + r;
                    float sv = s[sf][r] * SCALE;
                    sv = (kv > qrow) ? -INFINITY : sv;
                    s[sf][r] = sv;
                    mx = fmaxf(mx, sv);
                }
        } else {
#pragma unroll
            for (int sf = 0; sf < 4; sf++)
#pragma unroll
                for (int r = 0; r < 4; r++) {
                    float sv = s[sf][r] * SCALE;
                    s[sf][r] = sv;
                    mx = fmaxf(mx, sv);
                }
        }
        mx = fmaxf(mx, __shfl_xor(mx, 16, 64));
        mx = fmaxf(mx, __shfl_xor(mx, 32, 64));

        float mn = fmaxf(m_r, mx);
        float alpha = __expf(m_r - mn);
        m_r = mn;
        float p[4][4];
        float sum = 0.f;
#pragma unroll
        for (int sf = 0; sf < 4; sf++)
#pragma unroll
            for (int r = 0; r < 4; r++) {
                float pv = __expf(s[sf][r] - mn);
                p[sf][r] = pv;
                sum += pv;
            }
        sum += __shfl_xor(sum, 16, 64);
        sum += __shfl_xor(sum, 32, 64);
        l_r = l_r * alpha + sum;
#pragma unroll
        for (int hf = 0; hf < 8; hf++)
#pragma unroll
            for (int r = 0; r < 4; r++) acc[hf][r] *= alpha;

        // pack P^T to bf16 pairs, shuffle into PV B-frags (kv-major)
        unsigned pw[8];
#pragma unroll
        for (int sf = 0; sf < 4; sf++) {
            pw[2*sf]   = cvt_pk_bf16(p[sf][0], p[sf][1]);
            pw[2*sf+1] = cvt_pk_bf16(p[sf][2], p[sf][3]);
        }
        unsigned pbu[2][4];
        pbu[0][0]=0;pbu[0][1]=0;pbu[0][2]=0;pbu[0][3]=0;
        pbu[1][0]=0;pbu[1][1]=0;pbu[1][2]=0;pbu[1][3]=0;
        const int L1 = fr + 16 * ((fq & 1) * 2);
        const int L2 = L1 + 16;
        const int sel = (fq >> 1) & 1;
#pragma unroll
        for (int sf = 0; sf < 4; sf++) {
            unsigned w0 = (unsigned)__shfl((int)pw[2*sf],   L1, 64);
            unsigned w1 = (unsigned)__shfl((int)pw[2*sf+1], L1, 64);
            unsigned w2 = (unsigned)__shfl((int)pw[2*sf],   L2, 64);
            unsigned w3 = (unsigned)__shfl((int)pw[2*sf+1], L2, 64);
            if ((sf & 1) == sel) {
                int k2 = sf >> 1;
                pbu[k2][0] = w0; pbu[k2][1] = w1; pbu[k2][2] = w2; pbu[k2][3] = w3;
            }
        }
        union { unsigned u[4]; bf16x8 v; } pb0c, pb1c;
#pragma unroll
        for (int i = 0; i < 4; i++) { pb0c.u[i] = pbu[0][i]; pb1c.u[i] = pbu[1][i]; }
        bf16x8 pb0 = pb0c.v, pb1 = pb1c.v;

        // O^T += V^T P^T : A-frag rows h = hf*16+fr from swizzled v_lds
        __builtin_amdgcn_s_setprio(1);
#pragma unroll
        for (int hf = 0; hf < 8; hf++) {
            bf16x8 vf0 = *(const bf16x8*)(vl + hf*2048 + scol);
            bf16x8 vf1 = *(const bf16x8*)(vl + hf*2048 + (scol ^ 64));
            acc[hf] = __builtin_amdgcn_mfma_f32_16x16x32_bf16(vf0, pb0, acc[hf], 0, 0, 0);
            acc[hf] = __builtin_amdgcn_mfma_f32_16x16x32_bf16(vf1, pb1, acc[hf], 0, 0, 0);
        }
        __builtin_amdgcn_s_setprio(0);
        cur ^= 1;
    }

    // epilogue: O^T[h][q]: lane holds h = hf*16+fq*4+r, q = qrow
    unsigned short* po = (part == 0) ? po0 : (part == 1) ? po1 : po2;
    float linv = (l_r > 0.f) ? (1.0f / l_r) : 0.f;
    const long obase = ((long)b * T_ + qrow) * H_;
#pragma unroll
    for (int hf = 0; hf < 8; hf++) {
        unsigned u0 = cvt_pk_bf16(acc[hf][0] * linv, acc[hf][1] * linv);
        unsigned u1 = cvt_pk_bf16(acc[hf][2] * linv, acc[hf][3] * linv);
        uint2 uu; uu.x = u0; uu.y = u1;
        *(uint2*)(po + obase + hf*16 + fq*4) = uu;
    }
    if (fq == 0) {
        pm[part * 16384 + b * T_ + qrow] = m_r;
        pl[part * 16384 + b * T_ + qrow] = l_r;
    }
}

// ---------------------------------------------------------------------------
// Kernel 4: combine the three KV-parts
// ---------------------------------------------------------------------------
__global__ __launch_bounds__(256) void combine_kernel(
        const unsigned short* __restrict__ po0,
        const unsigned short* __restrict__ po1,
        const unsigned short* __restrict__ po2,
        const float* __restrict__ pm, const float* __restrict__ pl,
        float* __restrict__ out) {
    int idx = blockIdx.x * 256 + threadIdx.x;   // 0..262143
    int row = idx >> 4;                          // b*T + q
    int seg = idx & 15;
    float m0 = pm[row], m1 = pm[16384 + row], m2 = pm[32768 + row];
    float l0 = pl[row], l1 = pl[16384 + row], l2 = pl[32768 + row];
    float m = fmaxf(fmaxf(m0, m1), m2);
    float w0 = (l0 > 0.f) ? __expf(m0 - m) * l0 : 0.f;
    float w1 = (l1 > 0.f) ? __expf(m1 - m) * l1 : 0.f;
    float w2 = (l2 > 0.f) ? __expf(m2 - m) * l2 : 0.f;
    float inv = 1.0f / (w0 + w1 + w2);
    w0 *= inv; w1 *= inv; w2 *= inv;
    long off = (long)row * H_ + seg * 8;
    unsigned short ua[8], ub[8], uc[8];
    *(uint4*)ua = *(const uint4*)(po0 + off);
    *(uint4*)ub = *(const uint4*)(po1 + off);
    *(uint4*)uc = *(const uint4*)(po2 + off);
    float* o = out + off;
#pragma unroll
    for (int j2 = 0; j2 < 8; j2++)
        o[j2] = w0 * bf2f(ua[j2]) + w1 * bf2f(ub[j2]) + w2 * bf2f(uc[j2]);
}

// ---------------------------------------------------------------------------
extern "C" void kernel_launch(void* const* d_in, const int* in_sizes, int n_in,
                              void* d_out, int out_size, void* d_ws, size_t ws_size,
                              hipStream_t stream) {
    (void)in_sizes; (void)n_in; (void)out_size; (void)ws_size;
    const float* x  = (const float*)d_in[0];
    const float* Wk = (const float*)d_in[1];
    const float* Wq = (const float*)d_in[2];
    const float* Wv = (const float*)d_in[3];
    float* out = (float*)d_out;

    // ws layout (shorts). pm/pl alias Wt (dead by flash time); po2 aliases
    // the qkv v-region (dead after vtrans). Total ~25.9 MB.
    unsigned short* Wt  = (unsigned short*)d_ws;       // 393216 shorts
    unsigned short* qkv = Wt + 393216;                 // 3 x 2097152 (k,q,v)
    unsigned short* vT  = qkv + 6291456;               // 2097152
    unsigned short* po0 = vT + 2097152;                // 2097152
    unsigned short* po1 = po0 + 2097152;               // 2097152
    unsigned short* po2 = qkv + 4194304;               // aliases v region
    float* pm = (float*)d_ws;                          // 49152 floats (alias Wt)
    float* pl = pm + 49152;                            // 49152 floats (alias Wt)

    wtrans_kernel<<<1536, 256, 0, stream>>>(Wk, Wq, Wv, Wt);
    qkv_gemm<<<256, 256, 0, stream>>>(x, Wt, qkv);
    vtrans_kernel<<<256, 256, 0, stream>>>(qkv + 4194304, vT);
    flash5_kernel<<<768, 256, 0, stream>>>(qkv, vT, po0, po1, po2, pm, pl);
    combine_kernel<<<1024, 256, 0, stream>>>(po0, po1, po2, pm, pl, out);
}

// Round 6
// 96.514 us; speedup vs baseline: 2.2489x; 1.1265x over previous
//
#include <hip/hip_runtime.h>
#include <hip/hip_bf16.h>
#include <math.h>

// Problem constants
#define B_ 4
#define T_ 4096
#define C_ 1024
#define H_ 128
#define SCALE 0.08838834764831845f  // 1/sqrt(128)

typedef __attribute__((ext_vector_type(8))) short bf16x8;
typedef __attribute__((ext_vector_type(4))) float f32x4;

__device__ __forceinline__ unsigned short f2bf(float f) {
    union { float f; unsigned u; } x; x.f = f;
    unsigned r = x.u + 0x7FFF + ((x.u >> 16) & 1);
    return (unsigned short)(r >> 16);
}
__device__ __forceinline__ float bf2f(unsigned short u) {
    union { unsigned u; float f; } x; x.u = ((unsigned)u) << 16;
    return x.f;
}
__device__ __forceinline__ unsigned cvt_pk_bf16(float a, float b) {
    unsigned r;
    asm("v_cvt_pk_bf16_f32 %0, %1, %2" : "=v"(r) : "v"(a), "v"(b));
    return r;
}

// async global->LDS, 16B per lane. gsrc: per-lane global addr; ldst: wave-uniform base.
#define GLOAD16(gsrc, ldst)                                                        \
    __builtin_amdgcn_global_load_lds(                                              \
        (const __attribute__((address_space(1))) unsigned int*)(gsrc),             \
        (__attribute__((address_space(3))) unsigned int*)(ldst), 16, 0, 0)

// ---------------------------------------------------------------------------
// Kernel 1: W [C,H] fp32  ->  Wt [t][h][c] bf16  (transposed, cast)
// ---------------------------------------------------------------------------
__global__ __launch_bounds__(256) void wtrans_kernel(
        const float* __restrict__ Wk, const float* __restrict__ Wq,
        const float* __restrict__ Wv, unsigned short* __restrict__ Wt) {
    int tid = blockIdx.x * 256 + threadIdx.x;
    int t = tid >> 17;
    int r = tid & 131071;
    int c = r >> 7;
    int h = r & 127;
    const float* W = (t == 0) ? Wk : (t == 1) ? Wq : Wv;
    Wt[t * 131072 + h * 1024 + c] = f2bf(W[r]);
}

// ---------------------------------------------------------------------------
// Kernel 2: QKV projection GEMM.  M=16384, N=384, K=1024, bf16 MFMA.
// ---------------------------------------------------------------------------
__global__ __launch_bounds__(256) void qkv_gemm(
        const float* __restrict__ x, const unsigned short* __restrict__ Wt,
        unsigned short* __restrict__ qkv) {
    __shared__ unsigned short As[64][72];
    __shared__ unsigned short Bs[384][72];

    const int m0 = blockIdx.x * 64;
    const int tid = threadIdx.x;
    const int lane = tid & 63;
    const int w = tid >> 6;
    const int fr = lane & 15;
    const int fq = lane >> 4;

    f32x4 acc[6][4];
#pragma unroll
    for (int i = 0; i < 6; i++)
#pragma unroll
        for (int rf = 0; rf < 4; rf++) acc[i][rf] = f32x4{0.f, 0.f, 0.f, 0.f};

    for (int k0 = 0; k0 < C_; k0 += 64) {
        __syncthreads();
        {
            int row = tid >> 2;
            int coff = (tid & 3) * 16;
            const float* src = x + (long)(m0 + row) * C_ + k0 + coff;
            unsigned short tmp[16];
#pragma unroll
            for (int i = 0; i < 4; i++) {
                float4 v = ((const float4*)src)[i];
                tmp[i*4+0] = f2bf(v.x); tmp[i*4+1] = f2bf(v.y);
                tmp[i*4+2] = f2bf(v.z); tmp[i*4+3] = f2bf(v.w);
            }
            uint4* dst = (uint4*)&As[row][coff];
            dst[0] = ((uint4*)tmp)[0];
            dst[1] = ((uint4*)tmp)[1];
        }
#pragma unroll
        for (int i = 0; i < 12; i++) {
            int idx = tid + i * 256;
            int row = idx >> 3;
            int coff = (idx & 7) * 8;
            *(uint4*)&Bs[row][coff] =
                *(const uint4*)(Wt + (long)row * 1024 + k0 + coff);
        }
        __syncthreads();

#pragma unroll
        for (int kk = 0; kk < 2; kk++) {
            bf16x8 a[4], bb[6];
#pragma unroll
            for (int rf = 0; rf < 4; rf++)
                a[rf] = *(const bf16x8*)&As[rf*16 + fr][kk*32 + fq*8];
#pragma unroll
            for (int i = 0; i < 6; i++)
                bb[i] = *(const bf16x8*)&Bs[(w*6 + i)*16 + fr][kk*32 + fq*8];
#pragma unroll
            for (int i = 0; i < 6; i++)
#pragma unroll
                for (int rf = 0; rf < 4; rf++)
                    acc[i][rf] = __builtin_amdgcn_mfma_f32_16x16x32_bf16(
                        a[rf], bb[i], acc[i][rf], 0, 0, 0);
        }
    }
#pragma unroll
    for (int i = 0; i < 6; i++) {
        int nf = w*6 + i;
        int t = nf >> 3;
        int col = (nf & 7) * 16 + fr;
#pragma unroll
        for (int rf = 0; rf < 4; rf++)
#pragma unroll
            for (int r = 0; r < 4; r++) {
                int row = m0 + rf*16 + fq*4 + r;
                qkv[(long)t * (16384L * 128) + (long)row * 128 + col] = f2bf(acc[i][rf][r]);
            }
    }
}

// ---------------------------------------------------------------------------
// Kernel 2b: V [B*T][128] -> vT [B][128][T]  (bf16 transpose via LDS)
// ---------------------------------------------------------------------------
__global__ __launch_bounds__(256) void vtrans_kernel(
        const unsigned short* __restrict__ v, unsigned short* __restrict__ vT) {
    __shared__ unsigned short tile[64][136];
    const int t0 = (blockIdx.x & 63) * 64;
    const int b = blockIdx.x >> 6;
    const int tid = threadIdx.x;
#pragma unroll
    for (int i = 0; i < 4; i++) {
        int idx = tid + i * 256;
        int tr = idx >> 4, coff = (idx & 15) * 8;
        *(uint4*)&tile[tr][coff] =
            *(const uint4*)(v + ((long)(b * T_ + t0 + tr)) * H_ + coff);
    }
    __syncthreads();
#pragma unroll
    for (int i = 0; i < 4; i++) {
        int idx = tid + i * 256;
        int h = idx >> 3, ts = (idx & 7) * 8;
        unsigned short tmp[8];
#pragma unroll
        for (int j = 0; j < 8; j++) tmp[j] = tile[ts + j][h];
        *(uint4*)(vT + ((long)(b * H_ + h)) * T_ + t0 + ts) = *(uint4*)tmp;
    }
}

// ---------------------------------------------------------------------------
// Kernel 3: causal flash attention. QB=128, 8 waves (512 thr), KB=64,
// KV split-4. Swapped-QK^T in-register softmax + defer-max (THR=8).
// K,V via global_load_lds into double-buffered swizzled LDS (64 KB).
// Grid 512 = exactly 2 blocks/CU, all co-resident. Pairing n <-> n+256
// gives each CU complementary work (qt=jj with qt=31-jj).
// ---------------------------------------------------------------------------
__global__ __launch_bounds__(512, 4) void flash6_kernel(
        const unsigned short* __restrict__ qkv,
        const unsigned short* __restrict__ vT,
        unsigned short* __restrict__ po0, unsigned short* __restrict__ po1,
        unsigned short* __restrict__ po2, unsigned short* __restrict__ po3,
        float* __restrict__ pm, float* __restrict__ pl) {
    __shared__ unsigned short k_lds[2][64][128];   // 32 KB, swizzled
    __shared__ unsigned short v_lds[2][128][64];   // 32 KB, swizzled (v_lds[h][kv])

    const int n = blockIdx.x;                     // 0..511
    const int half = n >> 8;
    const int m = n & 255;
    const int b = (m & 7) >> 1;                   // XCD-batch affinity
    const int r = ((m >> 3) << 1) | (m & 1);      // 0..63
    const int jj = r & 31;
    const int pq = r >> 5;                        // 0..1
    const int qt = half ? (31 - jj) : jj;
    const int p = half * 2 + pq;                  // part 0..3
    const int q0 = qt * 128;
    const int ntt = (qt + 1) * 2;                 // KB=64 tiles in causal range
    const int t0 = (p * ntt) >> 2;
    const int t1 = ((p + 1) * ntt) >> 2;

    const int tid = threadIdx.x;
    const int w = tid >> 6;                       // 0..7
    const int lane = tid & 63;
    const int fr = lane & 15;
    const int fq = lane >> 4;

    const unsigned short* kbase = qkv + (long)b * T_ * H_;
    const unsigned short* vbase = vT + (long)b * H_ * T_;

    // ---- staging address constants ----
    // K: chunk c = 2w+i covers rows 4c..4c+3; lane -> (row 4c+(lane>>4), 16B col)
    const int kcolb0 = ((lane & 15) << 4) ^ ((((lane >> 4)) & 7) << 4);
    const int kcolb1 = ((lane & 15) << 4) ^ (((4 + (lane >> 4)) & 7) << 4);
    const int krl = lane >> 4;                    // 0..3
    // V: chunk c = 2w+i covers h-rows 8c..8c+7; lane -> (h 8c+(lane>>3), 16B col)
    const int vrl = lane >> 3;                    // 0..7
    const int vcolb = ((lane & 7) << 4) ^ (vrl << 4);
    unsigned short* const klds_flat = &k_lds[0][0][0];
    unsigned short* const vlds_flat = &v_lds[0][0][0];

    // MFMA read swizzle
    const int scol = ((fq ^ (fr & 7)) << 4);

    // Q as B-operand frags: col = fr -> q-row q0+w*16+fr
    bf16x8 qf[4];
    {
        const unsigned short* qptr = qkv + 2097152 + ((long)b*T_ + q0 + w*16 + fr) * H_;
#pragma unroll
        for (int ks = 0; ks < 4; ks++)
            qf[ks] = *(const bf16x8*)(qptr + ks*32 + fq*8);
    }

    f32x4 acc[8];
#pragma unroll
    for (int i = 0; i < 8; i++) acc[i] = f32x4{0.f, 0.f, 0.f, 0.f};
    float m_r = -INFINITY, l_r = 0.f;
    const int qrow = q0 + w*16 + fr;

    int cur = 0;
    if (t0 < t1) {
        const int kv0 = t0 * 64;
#pragma unroll
        for (int i = 0; i < 2; i++) {
            int kcolb = i ? kcolb1 : kcolb0;
            GLOAD16(kbase + (long)(kv0 + 8*w + 4*i + krl) * 128 + (kcolb >> 1),
                    klds_flat + w*1024 + i*512);
            GLOAD16(vbase + (long)(16*w + 8*i + vrl) * 4096 + kv0 + (vcolb >> 1),
                    vlds_flat + w*1024 + i*512);
        }
    }

    for (int t = t0; t < t1; ++t) {
        const int kv0 = t * 64;
        __syncthreads();   // all waves done reading buf[cur^1]
        if (t + 1 < t1) {
            const int kv0n = kv0 + 64;
            const int boff = (cur ^ 1) * 8192;
#pragma unroll
            for (int i = 0; i < 2; i++) {
                int kcolb = i ? kcolb1 : kcolb0;
                GLOAD16(kbase + (long)(kv0n + 8*w + 4*i + krl) * 128 + (kcolb >> 1),
                        klds_flat + boff + w*1024 + i*512);
                GLOAD16(vbase + (long)(16*w + 8*i + vrl) * 4096 + kv0n + (vcolb >> 1),
                        vlds_flat + boff + w*1024 + i*512);
            }
            asm volatile("s_waitcnt vmcnt(4)" ::: "memory");  // own tile-t loads done
        } else {
            asm volatile("s_waitcnt vmcnt(0)" ::: "memory");
        }
        __syncthreads();   // tile t visible in LDS

        const char* kl = (const char*)k_lds + cur*16384 + fr*256;
        const char* vl = (const char*)v_lds + cur*16384 + fr*128;

        // S^T = K Q^T
        f32x4 s[4];
#pragma unroll
        for (int sf = 0; sf < 4; sf++) s[sf] = f32x4{0.f,0.f,0.f,0.f};
        __builtin_amdgcn_s_setprio(1);
#pragma unroll
        for (int sf = 0; sf < 4; sf++)
#pragma unroll
            for (int ks = 0; ks < 4; ks++) {
                bf16x8 kf = *(const bf16x8*)(kl + sf*4096 + (scol ^ (ks << 6)));
                s[sf] = __builtin_amdgcn_mfma_f32_16x16x32_bf16(kf, qf[ks], s[sf], 0, 0, 0);
            }
        __builtin_amdgcn_s_setprio(0);

        // scale + causal mask (only tiles crossing this wave's rows) + reduce
        float mx = -INFINITY;
        if (kv0 + 63 > q0 + 16*w) {
#pragma unroll
            for (int sf = 0; sf < 4; sf++)
#pragma unroll
                for (int rr = 0; rr < 4; rr++) {
                    int kv = kv0 + sf*16 + fq*4 + rr;
                    float sv = s[sf][rr] * SCALE;
                    sv = (kv > qrow) ? -INFINITY : sv;
                    s[sf][rr] = sv;
                    mx = fmaxf(mx, sv);
                }
        } else {
#pragma unroll
            for (int sf = 0; sf < 4; sf++)
#pragma unroll
                for (int rr = 0; rr < 4; rr++) {
                    float sv = s[sf][rr] * SCALE;
                    s[sf][rr] = sv;
                    mx = fmaxf(mx, sv);
                }
        }
        mx = fmaxf(mx, __shfl_xor(mx, 16, 64));
        mx = fmaxf(mx, __shfl_xor(mx, 32, 64));

        // defer-max: skip rescale when max growth <= 8 (and history valid)
        const bool skip = __all((m_r > -1e37f) & (mx - m_r <= 8.f));
        float msub;
        if (skip) {
            msub = m_r;
        } else {
            float mn = fmaxf(m_r, mx);
            msub = (mn == -INFINITY) ? 0.f : mn;
            float alpha = __expf(m_r - msub);
            m_r = mn;
#pragma unroll
            for (int hf = 0; hf < 8; hf++)
#pragma unroll
                for (int rr = 0; rr < 4; rr++) acc[hf][rr] *= alpha;
            l_r *= alpha;
        }

        float pv[4][4];
        float sum = 0.f;
#pragma unroll
        for (int sf = 0; sf < 4; sf++)
#pragma unroll
            for (int rr = 0; rr < 4; rr++) {
                float e = __expf(s[sf][rr] - msub);
                pv[sf][rr] = e;
                sum += e;
            }
        sum += __shfl_xor(sum, 16, 64);
        sum += __shfl_xor(sum, 32, 64);
        l_r += sum;

        // pack P^T to bf16 pairs, shuffle into PV B-frags (kv-major)
        unsigned pw[8];
#pragma unroll
        for (int sf = 0; sf < 4; sf++) {
            pw[2*sf]   = cvt_pk_bf16(pv[sf][0], pv[sf][1]);
            pw[2*sf+1] = cvt_pk_bf16(pv[sf][2], pv[sf][3]);
        }
        unsigned pbu[2][4];
        pbu[0][0]=0;pbu[0][1]=0;pbu[0][2]=0;pbu[0][3]=0;
        pbu[1][0]=0;pbu[1][1]=0;pbu[1][2]=0;pbu[1][3]=0;
        const int L1 = fr + 16 * ((fq & 1) * 2);
        const int L2 = L1 + 16;
        const int sel = (fq >> 1) & 1;
#pragma unroll
        for (int sf = 0; sf < 4; sf++) {
            unsigned w0 = (unsigned)__shfl((int)pw[2*sf],   L1, 64);
            unsigned w1 = (unsigned)__shfl((int)pw[2*sf+1], L1, 64);
            unsigned w2 = (unsigned)__shfl((int)pw[2*sf],   L2, 64);
            unsigned w3 = (unsigned)__shfl((int)pw[2*sf+1], L2, 64);
            if ((sf & 1) == sel) {
                int k2 = sf >> 1;
                pbu[k2][0] = w0; pbu[k2][1] = w1; pbu[k2][2] = w2; pbu[k2][3] = w3;
            }
        }
        union { unsigned u[4]; bf16x8 v; } pb0c, pb1c;
#pragma unroll
        for (int i = 0; i < 4; i++) { pb0c.u[i] = pbu[0][i]; pb1c.u[i] = pbu[1][i]; }
        bf16x8 pb0 = pb0c.v, pb1 = pb1c.v;

        // O^T += V^T P^T
        __builtin_amdgcn_s_setprio(1);
#pragma unroll
        for (int hf = 0; hf < 8; hf++) {
            bf16x8 vf0 = *(const bf16x8*)(vl + hf*2048 + scol);
            bf16x8 vf1 = *(const bf16x8*)(vl + hf*2048 + (scol ^ 64));
            acc[hf] = __builtin_amdgcn_mfma_f32_16x16x32_bf16(vf0, pb0, acc[hf], 0, 0, 0);
            acc[hf] = __builtin_amdgcn_mfma_f32_16x16x32_bf16(vf1, pb1, acc[hf], 0, 0, 0);
        }
        __builtin_amdgcn_s_setprio(0);
        cur ^= 1;
    }

    // epilogue
    unsigned short* po = (p == 0) ? po0 : (p == 1) ? po1 : (p == 2) ? po2 : po3;
    float linv = (l_r > 0.f) ? (1.0f / l_r) : 0.f;
    const long obase = ((long)b * T_ + qrow) * H_;
#pragma unroll
    for (int hf = 0; hf < 8; hf++) {
        unsigned u0 = cvt_pk_bf16(acc[hf][0] * linv, acc[hf][1] * linv);
        unsigned u1 = cvt_pk_bf16(acc[hf][2] * linv, acc[hf][3] * linv);
        uint2 uu; uu.x = u0; uu.y = u1;
        *(uint2*)(po + obase + hf*16 + fq*4) = uu;
    }
    if (fq == 0) {
        pm[p * 16384 + b * T_ + qrow] = m_r;
        pl[p * 16384 + b * T_ + qrow] = l_r;
    }
}

// ---------------------------------------------------------------------------
// Kernel 4: combine the four KV-parts
// ---------------------------------------------------------------------------
__global__ __launch_bounds__(256) void combine_kernel(
        const unsigned short* __restrict__ po0,
        const unsigned short* __restrict__ po1,
        const unsigned short* __restrict__ po2,
        const unsigned short* __restrict__ po3,
        const float* __restrict__ pm, const float* __restrict__ pl,
        float* __restrict__ out) {
    int idx = blockIdx.x * 256 + threadIdx.x;   // 0..262143
    int row = idx >> 4;                          // b*T + q
    int seg = idx & 15;
    float mv[4], lv[4];
#pragma unroll
    for (int i = 0; i < 4; i++) { mv[i] = pm[i*16384 + row]; lv[i] = pl[i*16384 + row]; }
    float m = fmaxf(fmaxf(mv[0], mv[1]), fmaxf(mv[2], mv[3]));
    float wv[4]; float tot = 0.f;
#pragma unroll
    for (int i = 0; i < 4; i++) {
        wv[i] = (lv[i] > 0.f) ? __expf(mv[i] - m) * lv[i] : 0.f;
        tot += wv[i];
    }
    float inv = 1.0f / tot;
    long off = (long)row * H_ + seg * 8;
    unsigned short ua[8], ub[8], uc[8], ud[8];
    *(uint4*)ua = *(const uint4*)(po0 + off);
    *(uint4*)ub = *(const uint4*)(po1 + off);
    *(uint4*)uc = *(const uint4*)(po2 + off);
    *(uint4*)ud = *(const uint4*)(po3 + off);
    float* o = out + off;
#pragma unroll
    for (int j2 = 0; j2 < 8; j2++)
        o[j2] = inv * (wv[0] * bf2f(ua[j2]) + wv[1] * bf2f(ub[j2]) +
                       wv[2] * bf2f(uc[j2]) + wv[3] * bf2f(ud[j2]));
}

// ---------------------------------------------------------------------------
extern "C" void kernel_launch(void* const* d_in, const int* in_sizes, int n_in,
                              void* d_out, int out_size, void* d_ws, size_t ws_size,
                              hipStream_t stream) {
    (void)in_sizes; (void)n_in; (void)out_size; (void)ws_size;
    const float* x  = (const float*)d_in[0];
    const float* Wk = (const float*)d_in[1];
    const float* Wq = (const float*)d_in[2];
    const float* Wv = (const float*)d_in[3];
    float* out = (float*)d_out;

    // ws layout (shorts). pm/pl alias Wt (dead after gemm); po2 aliases the
    // qkv v-region (dead after vtrans). Total ~30 MB.
    unsigned short* Wt  = (unsigned short*)d_ws;       // 393216 shorts
    unsigned short* qkv = Wt + 393216;                 // 3 x 2097152 (k,q,v)
    unsigned short* vT  = qkv + 6291456;               // 2097152
    unsigned short* po0 = vT + 2097152;                // 2097152
    unsigned short* po1 = po0 + 2097152;               // 2097152
    unsigned short* po3 = po1 + 2097152;               // 2097152
    unsigned short* po2 = qkv + 4194304;               // aliases v region
    float* pm = (float*)d_ws;                          // 65536 floats (alias Wt)
    float* pl = pm + 65536;                            // 65536 floats (alias Wt)

    wtrans_kernel<<<1536, 256, 0, stream>>>(Wk, Wq, Wv, Wt);
    qkv_gemm<<<256, 256, 0, stream>>>(x, Wt, qkv);
    vtrans_kernel<<<256, 256, 0, stream>>>(qkv + 4194304, vT);
    flash6_kernel<<<512, 512, 0, stream>>>(qkv, vT, po0, po1, po2, po3, pm, pl);
    combine_kernel<<<1024, 256, 0, stream>>>(po0, po1, po2, po3, pm, pl, out);
}